// Round 13
// baseline (202.858 us; speedup 1.0000x reference)
//
#include <hip/hip_runtime.h>
#include <hip/hip_bf16.h>
#include <hip/hip_cooperative_groups.h>
#include <stdint.h>

// KGEdges round 13 — SINGLE cooperative kernel (convert -> grid.sync -> proj ->
// grid.sync -> edge). R12 post-mortem: dbuf proj moved dur by 0.00 us; R9->R10
// showed -12 us/dispatch; kernels sum ~25 us vs dur 104 => launch/gap overhead
// dominates. Only lever left: dispatch count -> 1. Guide: cooperative launch is
// supported by the grading harness. All three phase bodies are the proven R12
// ones (bit-exact absmax 0.015625 since R8).
// Semantics: out[b,i,j] = sum_d w_out[d]*tanh(head[b,j,d]+child[b,i,d]) + mm_i
// + mm_j; head=enc@Wh^T+bh, child=enc@Wc^T; fp32 in / int32 mask / fp32 out.
// Exp-domain identity: sum w*tanh = S + sum(-2w)*rcp(Eh*Ec+1), E=exp2(K*x).

namespace cg = cooperative_groups;

typedef __bf16 bf16_t;
typedef __attribute__((ext_vector_type(8))) __bf16 bf16x8;
typedef __attribute__((ext_vector_type(4))) float f32x4;

#define SL 256
#define ENC 1024
#define NTOT 512
#define N_ENC 2097152   // 8*256*1024
#define N_W 262144      // 256*1024
#define KSCALE 2.8853900817779268f  // 2*log2(e)
#define LSTR 260

__device__ __forceinline__ void async16(void* lds, const void* g) {
  __builtin_amdgcn_global_load_lds(
      (const __attribute__((address_space(1))) uint32_t*)g,
      (__attribute__((address_space(3))) uint32_t*)lds, 16, 0, 0);
}
__device__ __forceinline__ unsigned short f32_to_bf16_rne(float f) {
  uint32_t u = __float_as_uint(f);
  return (unsigned short)((u + 0x7FFFu + ((u >> 16) & 1u)) >> 16);
}

union SMem {
  struct { bf16_t As[2][2048]; bf16_t Bs[2][2048]; } p;                    // 16 KB
  struct { float ldH[32 * LSTR]; float ldC[32 * LSTR]; float wS[256]; float red[256]; } e;  // 68.6 KB
};

__global__ __launch_bounds__(256)
void fused_coop(const float* __restrict__ enc, const int* __restrict__ mask,
                const float* __restrict__ Wh, const float* __restrict__ bh,
                const float* __restrict__ Wc, const float* __restrict__ wout,
                float* __restrict__ hc, unsigned short* __restrict__ encB,
                unsigned short* __restrict__ WB, float* __restrict__ out) {
  __shared__ SMem sm;
  cg::grid_group grid = cg::this_grid();
  const int bid = blockIdx.x;   // 256 blocks, 1 per CU
  const int t = threadIdx.x;

  // ================= phase 1: fp32 -> bf16 convert (grid-stride) =================
#pragma unroll
  for (int k = 0; k < 10; ++k) {  // 655360 f32x4 total / 65536 threads = 10
    int gi = ((bid * 256 + t) + k * 65536) * 4;
    const float* src;
    unsigned short* dst;
    int off;
    if (gi < N_ENC) {
      src = enc; off = gi; dst = encB + gi;
    } else if (gi < N_ENC + N_W) {
      src = Wh; off = gi - N_ENC; dst = WB + off;
    } else {
      src = Wc; off = gi - N_ENC - N_W; dst = WB + N_W + off;
    }
    f32x4 v = *(const f32x4*)(src + off);
    ushort4 o;
    o.x = f32_to_bf16_rne(v[0]); o.y = f32_to_bf16_rne(v[1]);
    o.z = f32_to_bf16_rne(v[2]); o.w = f32_to_bf16_rne(v[3]);
    *(ushort4*)dst = o;
  }
  grid.sync();  // publish encB/WB device-wide

  // ================= phase 2: MFMA proj (R12 dbuf body, bit-proven) =================
  {
    const int wv = t >> 6, lane = t & 63;
    const int m0 = (bid & 31) * 64;   // 32 m-tiles
    const int n0 = (bid >> 5) * 64;   // 8 n-tiles
    const int srow = t >> 2, schunk = t & 3;
    const int mq = (wv & 1) * 32, nq = (wv >> 1) * 32;
    const int fr = lane & 15, kq = lane >> 4;

    f32x4 acc00 = {0.f, 0.f, 0.f, 0.f};
    f32x4 acc01 = acc00, acc10 = acc00, acc11 = acc00;

    const unsigned short* gA = encB + (size_t)(m0 + srow) * ENC + schunk * 8;
    const unsigned short* gB = WB + (size_t)(n0 + srow) * ENC + schunk * 8;

    async16(&sm.p.As[0][wv * 512], gA);
    async16(&sm.p.Bs[0][wv * 512], gB);

#pragma unroll 4
    for (int i = 0; i < 32; ++i) {
      const int buf = i & 1;
      __syncthreads();  // drains async16 for `buf`, publishes it
      if (i + 1 < 32) {
        const int k1 = (i + 1) * 32;
        async16(&sm.p.As[buf ^ 1][wv * 512], gA + k1);
        async16(&sm.p.Bs[buf ^ 1][wv * 512], gB + k1);
      }
      bf16x8 a0 = *(const bf16x8*)&sm.p.As[buf][(mq + fr) * 32 + kq * 8];
      bf16x8 a1 = *(const bf16x8*)&sm.p.As[buf][(mq + 16 + fr) * 32 + kq * 8];
      bf16x8 b0 = *(const bf16x8*)&sm.p.Bs[buf][(nq + fr) * 32 + kq * 8];
      bf16x8 b1 = *(const bf16x8*)&sm.p.Bs[buf][(nq + 16 + fr) * 32 + kq * 8];
      acc00 = __builtin_amdgcn_mfma_f32_16x16x32_bf16(a0, b0, acc00, 0, 0, 0);
      acc01 = __builtin_amdgcn_mfma_f32_16x16x32_bf16(a0, b1, acc01, 0, 0, 0);
      acc10 = __builtin_amdgcn_mfma_f32_16x16x32_bf16(a1, b0, acc10, 0, 0, 0);
      acc11 = __builtin_amdgcn_mfma_f32_16x16x32_bf16(a1, b1, acc11, 0, 0, 0);
    }
    // C/D: col=lane&15, row=(lane>>4)*4+r (bit-proven)
    const int colA = n0 + nq + fr;
    const int colB = colA + 16;
    const float biasA = (colA < 256) ? bh[colA] : 0.0f;
    const float biasB = (colB < 256) ? bh[colB] : 0.0f;
#pragma unroll
    for (int r = 0; r < 4; ++r) {
      int row0 = m0 + mq + kq * 4 + r;
      int row1 = row0 + 16;
      hc[(size_t)row0 * NTOT + colA] = __builtin_amdgcn_exp2f(KSCALE * (acc00[r] + biasA));
      hc[(size_t)row0 * NTOT + colB] = __builtin_amdgcn_exp2f(KSCALE * (acc01[r] + biasB));
      hc[(size_t)row1 * NTOT + colA] = __builtin_amdgcn_exp2f(KSCALE * (acc10[r] + biasA));
      hc[(size_t)row1 * NTOT + colB] = __builtin_amdgcn_exp2f(KSCALE * (acc11[r] + biasB));
    }
  }
  grid.sync();  // publish hc device-wide

  // ================= phase 3: edge (R10 body, proven), 2 tiles/block =================
  for (int tile = bid; tile < 512; tile += 256) {
    __syncthreads();  // LDS reuse across phases/tiles
    const int b = tile >> 6;
    const int i0 = ((tile >> 3) & 7) * 32;
    const int j0 = (tile & 7) * 32;
    const int sbase = b * SL;

    float w = wout[t];
    sm.e.wS[t] = -2.0f * w;
    sm.e.red[t] = w;

    for (int u = t; u < 32 * 64; u += 256) {
      int row = u >> 6;
      int c4 = (u & 63) << 2;
      f32x4 hv = *(const f32x4*)&hc[(size_t)(sbase + j0 + row) * NTOT + c4];        // Eh(j)
      f32x4 cv = *(const f32x4*)&hc[(size_t)(sbase + i0 + row) * NTOT + 256 + c4];  // Ec(i)
      *(f32x4*)&sm.e.ldH[row * LSTR + c4] = hv;
      *(f32x4*)&sm.e.ldC[row * LSTR + c4] = cv;
    }
    __syncthreads();
    for (int s = 128; s > 0; s >>= 1) {
      if (t < s) sm.e.red[t] += sm.e.red[t + s];
      __syncthreads();
    }
    const float S = sm.e.red[0];

    const int tx = t & 15, ty = t >> 4;
    const float* hp0 = &sm.e.ldH[tx * LSTR];
    const float* hp1 = &sm.e.ldH[(tx + 16) * LSTR];
    const float* cp0 = &sm.e.ldC[ty * LSTR];
    const float* cp1 = &sm.e.ldC[(ty + 16) * LSTR];
    float a00 = 0.f, a01 = 0.f, a10 = 0.f, a11 = 0.f;

#pragma unroll 8
    for (int d = 0; d < 256; d += 4) {
      f32x4 h0 = *(const f32x4*)&hp0[d];
      f32x4 h1 = *(const f32x4*)&hp1[d];
      f32x4 c0 = *(const f32x4*)&cp0[d];
      f32x4 c1 = *(const f32x4*)&cp1[d];
      f32x4 w4 = *(const f32x4*)&sm.e.wS[d];  // uniform addr -> LDS broadcast
#pragma unroll
      for (int e = 0; e < 4; ++e) {
        float he0 = h0[e], he1 = h1[e], ce0 = c0[e], ce1 = c1[e], we = w4[e];
        float r00 = __builtin_amdgcn_rcpf(ce0 * he0 + 1.0f);
        float r01 = __builtin_amdgcn_rcpf(ce0 * he1 + 1.0f);
        float r10 = __builtin_amdgcn_rcpf(ce1 * he0 + 1.0f);
        float r11 = __builtin_amdgcn_rcpf(ce1 * he1 + 1.0f);
        a00 = fmaf(we, r00, a00);
        a01 = fmaf(we, r01, a01);
        a10 = fmaf(we, r10, a10);
        a11 = fmaf(we, r11, a11);
      }
    }

    const int gi0 = sbase + i0 + ty, gi1 = gi0 + 16;
    const int gj0 = j0 + tx, gj1 = gj0 + 16;
    const float mi0 = (1.0f - (float)mask[gi0]) * -1.0e8f;
    const float mi1 = (1.0f - (float)mask[gi1]) * -1.0e8f;
    const float mj0 = (1.0f - (float)mask[sbase + gj0]) * -1.0e8f;
    const float mj1 = (1.0f - (float)mask[sbase + gj1]) * -1.0e8f;
    out[(size_t)gi0 * SL + gj0] = S + a00 + mi0 + mj0;
    out[(size_t)gi0 * SL + gj1] = S + a01 + mi0 + mj1;
    out[(size_t)gi1 * SL + gj0] = S + a10 + mi1 + mj0;
    out[(size_t)gi1 * SL + gj1] = S + a11 + mi1 + mj1;
  }
}

// ================= Fallback: R12 3-kernel pipeline (proven 104 us) =================
__global__ __launch_bounds__(256)
void convert_kernel(const float* __restrict__ enc, const float* __restrict__ Wh,
                    const float* __restrict__ Wc,
                    unsigned short* __restrict__ encB, unsigned short* __restrict__ WB) {
  int gi = (blockIdx.x * 256 + threadIdx.x) * 4;
  const float* src;
  unsigned short* dst;
  int off;
  if (gi < N_ENC) { src = enc; off = gi; dst = encB + gi; }
  else if (gi < N_ENC + N_W) { src = Wh; off = gi - N_ENC; dst = WB + off; }
  else { src = Wc; off = gi - N_ENC - N_W; dst = WB + N_W + off; }
  f32x4 v = *(const f32x4*)(src + off);
  ushort4 o;
  o.x = f32_to_bf16_rne(v[0]); o.y = f32_to_bf16_rne(v[1]);
  o.z = f32_to_bf16_rne(v[2]); o.w = f32_to_bf16_rne(v[3]);
  *(ushort4*)dst = o;
}

__global__ __launch_bounds__(256)
void proj_kernel(const unsigned short* __restrict__ A, const unsigned short* __restrict__ WB,
                 const float* __restrict__ bh, float* __restrict__ hc) {
  __shared__ bf16_t As[2][64 * 32];
  __shared__ bf16_t Bs[2][64 * 32];
  const int t = threadIdx.x;
  const int wv = t >> 6, lane = t & 63;
  const int m0 = blockIdx.x * 64;
  const int n0 = blockIdx.y * 64;
  const int srow = t >> 2, schunk = t & 3;
  const int mq = (wv & 1) * 32, nq = (wv >> 1) * 32;
  const int fr = lane & 15, kq = lane >> 4;
  f32x4 acc00 = {0.f, 0.f, 0.f, 0.f};
  f32x4 acc01 = acc00, acc10 = acc00, acc11 = acc00;
  const unsigned short* gA = A + (size_t)(m0 + srow) * ENC + schunk * 8;
  const unsigned short* gB = WB + (size_t)(n0 + srow) * ENC + schunk * 8;
  async16(&As[0][wv * 512], gA);
  async16(&Bs[0][wv * 512], gB);
#pragma unroll 4
  for (int i = 0; i < 32; ++i) {
    const int buf = i & 1;
    __syncthreads();
    if (i + 1 < 32) {
      const int k1 = (i + 1) * 32;
      async16(&As[buf ^ 1][wv * 512], gA + k1);
      async16(&Bs[buf ^ 1][wv * 512], gB + k1);
    }
    bf16x8 a0 = *(const bf16x8*)&As[buf][(mq + fr) * 32 + kq * 8];
    bf16x8 a1 = *(const bf16x8*)&As[buf][(mq + 16 + fr) * 32 + kq * 8];
    bf16x8 b0 = *(const bf16x8*)&Bs[buf][(nq + fr) * 32 + kq * 8];
    bf16x8 b1 = *(const bf16x8*)&Bs[buf][(nq + 16 + fr) * 32 + kq * 8];
    acc00 = __builtin_amdgcn_mfma_f32_16x16x32_bf16(a0, b0, acc00, 0, 0, 0);
    acc01 = __builtin_amdgcn_mfma_f32_16x16x32_bf16(a0, b1, acc01, 0, 0, 0);
    acc10 = __builtin_amdgcn_mfma_f32_16x16x32_bf16(a1, b0, acc10, 0, 0, 0);
    acc11 = __builtin_amdgcn_mfma_f32_16x16x32_bf16(a1, b1, acc11, 0, 0, 0);
  }
  const int colA = n0 + nq + fr;
  const int colB = colA + 16;
  const float biasA = (colA < 256) ? bh[colA] : 0.0f;
  const float biasB = (colB < 256) ? bh[colB] : 0.0f;
#pragma unroll
  for (int r = 0; r < 4; ++r) {
    int row0 = m0 + mq + kq * 4 + r;
    int row1 = row0 + 16;
    hc[(size_t)row0 * NTOT + colA] = __builtin_amdgcn_exp2f(KSCALE * (acc00[r] + biasA));
    hc[(size_t)row0 * NTOT + colB] = __builtin_amdgcn_exp2f(KSCALE * (acc01[r] + biasB));
    hc[(size_t)row1 * NTOT + colA] = __builtin_amdgcn_exp2f(KSCALE * (acc10[r] + biasA));
    hc[(size_t)row1 * NTOT + colB] = __builtin_amdgcn_exp2f(KSCALE * (acc11[r] + biasB));
  }
}

__global__ __launch_bounds__(256)
void edge_kernel(const float* __restrict__ hc, const float* __restrict__ wout,
                 const int* __restrict__ mask, float* __restrict__ out) {
  __shared__ float ldH[32 * LSTR];
  __shared__ float ldC[32 * LSTR];
  __shared__ float wS[256];
  __shared__ float red[256];
  const int t = threadIdx.x;
  const int b = blockIdx.z;
  const int i0 = blockIdx.y * 32;
  const int j0 = blockIdx.x * 32;
  const int sbase = b * SL;
  float w = wout[t];
  wS[t] = -2.0f * w;
  red[t] = w;
  for (int u = t; u < 32 * 64; u += 256) {
    int row = u >> 6;
    int c4 = (u & 63) << 2;
    f32x4 hv = *(const f32x4*)&hc[(size_t)(sbase + j0 + row) * NTOT + c4];
    f32x4 cv = *(const f32x4*)&hc[(size_t)(sbase + i0 + row) * NTOT + 256 + c4];
    *(f32x4*)&ldH[row * LSTR + c4] = hv;
    *(f32x4*)&ldC[row * LSTR + c4] = cv;
  }
  __syncthreads();
  for (int s = 128; s > 0; s >>= 1) {
    if (t < s) red[t] += red[t + s];
    __syncthreads();
  }
  const float S = red[0];
  const int tx = t & 15, ty = t >> 4;
  const float* hp0 = &ldH[tx * LSTR];
  const float* hp1 = &ldH[(tx + 16) * LSTR];
  const float* cp0 = &ldC[ty * LSTR];
  const float* cp1 = &ldC[(ty + 16) * LSTR];
  float a00 = 0.f, a01 = 0.f, a10 = 0.f, a11 = 0.f;
#pragma unroll 8
  for (int d = 0; d < 256; d += 4) {
    f32x4 h0 = *(const f32x4*)&hp0[d];
    f32x4 h1 = *(const f32x4*)&hp1[d];
    f32x4 c0 = *(const f32x4*)&cp0[d];
    f32x4 c1 = *(const f32x4*)&cp1[d];
    f32x4 w4 = *(const f32x4*)&wS[d];
#pragma unroll
    for (int e = 0; e < 4; ++e) {
      float he0 = h0[e], he1 = h1[e], ce0 = c0[e], ce1 = c1[e], we = w4[e];
      float r00 = __builtin_amdgcn_rcpf(ce0 * he0 + 1.0f);
      float r01 = __builtin_amdgcn_rcpf(ce0 * he1 + 1.0f);
      float r10 = __builtin_amdgcn_rcpf(ce1 * he0 + 1.0f);
      float r11 = __builtin_amdgcn_rcpf(ce1 * he1 + 1.0f);
      a00 = fmaf(we, r00, a00);
      a01 = fmaf(we, r01, a01);
      a10 = fmaf(we, r10, a10);
      a11 = fmaf(we, r11, a11);
    }
  }
  const int gi0 = sbase + i0 + ty, gi1 = gi0 + 16;
  const int gj0 = j0 + tx, gj1 = gj0 + 16;
  const float mi0 = (1.0f - (float)mask[gi0]) * -1.0e8f;
  const float mi1 = (1.0f - (float)mask[gi1]) * -1.0e8f;
  const float mj0 = (1.0f - (float)mask[sbase + gj0]) * -1.0e8f;
  const float mj1 = (1.0f - (float)mask[sbase + gj1]) * -1.0e8f;
  out[(size_t)gi0 * SL + gj0] = S + a00 + mi0 + mj0;
  out[(size_t)gi0 * SL + gj1] = S + a01 + mi0 + mj1;
  out[(size_t)gi1 * SL + gj0] = S + a10 + mi1 + mj0;
  out[(size_t)gi1 * SL + gj1] = S + a11 + mi1 + mj1;
}

extern "C" void kernel_launch(void* const* d_in, const int* in_sizes, int n_in,
                              void* d_out, int out_size, void* d_ws, size_t ws_size,
                              hipStream_t stream) {
  (void)in_sizes; (void)n_in; (void)out_size; (void)ws_size;
  const float* enc = (const float*)d_in[0];   // (8,256,1024) fp32
  const int* mask = (const int*)d_in[1];      // (8,256) int32
  const float* Wh = (const float*)d_in[2];    // (256,1024) fp32
  const float* bh = (const float*)d_in[3];    // (256,) fp32
  const float* Wc = (const float*)d_in[4];    // (256,1024) fp32
  const float* wout = (const float*)d_in[5];  // (256,) fp32
  float* out = (float*)d_out;

  char* W = (char*)d_ws;
  float* hc = (float*)W;                                   // 4 MiB
  unsigned short* encB = (unsigned short*)(W + (4 << 20)); // 4 MiB
  unsigned short* WB = (unsigned short*)(W + (8 << 20));   // 1 MiB

  void* args[] = {(void*)&enc, (void*)&mask, (void*)&Wh, (void*)&bh,
                  (void*)&Wc, (void*)&wout, (void*)&hc, (void*)&encB,
                  (void*)&WB, (void*)&out};
  hipError_t err = hipLaunchCooperativeKernel((const void*)fused_coop,
                                              dim3(256), dim3(256), args, 0, stream);
  if (err != hipSuccess) {  // graph-safe host-side fallback: proven R12 pipeline
    convert_kernel<<<2560, 256, 0, stream>>>(enc, Wh, Wc, encB, WB);
    proj_kernel<<<dim3(32, 8), 256, 0, stream>>>(encB, WB, bh, hc);
    edge_kernel<<<dim3(8, 8, 8), 256, 0, stream>>>(hc, wout, mask, out);
  }
}

// Round 14
// 100.322 us; speedup vs baseline: 2.0221x; 2.0221x over previous
//
#include <hip/hip_runtime.h>
#include <hip/hip_bf16.h>
#include <stdint.h>

// KGEdges round 14 — 2 dispatches: software-pipelined fused convert+proj, then edge.
// R13 post-mortem: cooperative single-kernel = 118 us alone (grid.sync cost on
// 8 XCDs + 1 block/CU everywhere) — dead end. R12 (104.1 us) = ~85 us mandatory
// harness ws-poison fills + ~19 us kernels. This round compresses the kernel part:
// convert's 19 MB round-trip and one dispatch boundary are removed by fusing
// fp32->bf16 into proj staging with a register-prefetch pipeline (R11 failed this
// by serializing load->pack; here next-tile loads are issued BEFORE packing the
// current tile, so vmcnt drains only older loads while new ones fly ~250 cyc).
// Semantics (R8-R13 green, absmax 0.015625): out[b,i,j] = sum_d w_out[d]*
// tanh(head[b,j,d]+child[b,i,d]) + mm_i + mm_j; head=enc@Wh^T+bh, child=enc@Wc^T;
// fp32 in / int32 mask / fp32 out. Exp-domain: sum w*tanh = S + sum(-2w)*
// rcp(Eh*Ec+1), E=exp2(K*x), K=2log2(e).

typedef __bf16 bf16_t;
typedef __attribute__((ext_vector_type(8))) __bf16 bf16x8;
typedef __attribute__((ext_vector_type(4))) float f32x4;
typedef __attribute__((ext_vector_type(4))) uint32_t u32x4;

#define SL 256
#define ENC 1024
#define NTOT 512
#define KSCALE 2.8853900817779268f  // 2*log2(e)
#define LSTR 260

__device__ __forceinline__ uint32_t bfpack(float a, float b) {  // 2x f32 -> packed bf16 (RNE)
  uint32_t ua = __float_as_uint(a); ua = ua + 0x7FFFu + ((ua >> 16) & 1u);
  uint32_t ub = __float_as_uint(b); ub = ub + 0x7FFFu + ((ub >> 16) & 1u);
  return (ua >> 16) | (ub & 0xFFFF0000u);
}

// ---- projc: fused convert+proj, register-prefetch pipeline, dbuf LDS.
// hc[s][0:256]=exp2(K*(enc@Wh^T+bh)) [Eh], hc[s][256:512]=exp2(K*enc@Wc^T) [Ec]
// 64x64 tile, BK=32, 4 waves each 2x2 MFMA 16x16x32 bf16 (bit-proven maps).
__global__ __launch_bounds__(256)
void projc_kernel(const float* __restrict__ enc, const float* __restrict__ Wh,
                  const float* __restrict__ Wc, const float* __restrict__ bh,
                  float* __restrict__ hc) {
  __shared__ bf16_t As[2][2048];
  __shared__ bf16_t Bs[2][2048];
  const int t = threadIdx.x;
  const int wv = t >> 6, lane = t & 63;
  const int m0 = blockIdx.x * 64;   // 32 blocks (2048 rows)
  const int n0 = blockIdx.y * 64;   // 8 blocks (512 cols of [head|child])
  const int srow = t >> 2;          // staging row 0..63
  const int sch = (t & 3) * 8;      // fp32 elem offset in row (0/8/16/24)
  const int mq = (wv & 1) * 32, nq = (wv >> 1) * 32;
  const int fr = lane & 15, kq = lane >> 4;

  f32x4 acc00 = {0.f, 0.f, 0.f, 0.f};
  f32x4 acc01 = acc00, acc10 = acc00, acc11 = acc00;

  const float* gA = enc + (size_t)(m0 + srow) * ENC + sch;
  const float* gW = ((n0 < 256) ? Wh + (size_t)(n0 + srow) * ENC
                                : Wc + (size_t)(n0 - 256 + srow) * ENC) + sch;

  // prologue: load k-tile 0 into registers
  f32x4 a0 = *(const f32x4*)(gA);
  f32x4 a1 = *(const f32x4*)(gA + 4);
  f32x4 w0 = *(const f32x4*)(gW);
  f32x4 w1 = *(const f32x4*)(gW + 4);

#pragma unroll 2
  for (int i = 0; i < 32; ++i) {
    const int buf = i & 1;
    // issue NEXT tile's loads first — they fly across pack+write+barrier+MFMA
    f32x4 na0, na1, nw0, nw1;
    if (i + 1 < 32) {
      const int k1 = (i + 1) * 32;
      na0 = *(const f32x4*)(gA + k1);
      na1 = *(const f32x4*)(gA + k1 + 4);
      nw0 = *(const f32x4*)(gW + k1);
      nw1 = *(const f32x4*)(gW + k1 + 4);
    }
    // pack current (vmcnt waits only on the older loads) and stage to LDS
    u32x4 Au = {bfpack(a0[0], a0[1]), bfpack(a0[2], a0[3]),
                bfpack(a1[0], a1[1]), bfpack(a1[2], a1[3])};
    u32x4 Wu = {bfpack(w0[0], w0[1]), bfpack(w0[2], w0[3]),
                bfpack(w1[0], w1[1]), bfpack(w1[2], w1[3])};
    *(u32x4*)&As[buf][t * 8] = Au;   // byte offset t*16, stride-32 rows (bit-proven)
    *(u32x4*)&Bs[buf][t * 8] = Wu;
    __syncthreads();  // publish buf; also fences write(i+1,~buf) from read(i-1,~buf)
    bf16x8 fa0 = *(const bf16x8*)&As[buf][(mq + fr) * 32 + kq * 8];
    bf16x8 fa1 = *(const bf16x8*)&As[buf][(mq + 16 + fr) * 32 + kq * 8];
    bf16x8 fb0 = *(const bf16x8*)&Bs[buf][(nq + fr) * 32 + kq * 8];
    bf16x8 fb1 = *(const bf16x8*)&Bs[buf][(nq + 16 + fr) * 32 + kq * 8];
    acc00 = __builtin_amdgcn_mfma_f32_16x16x32_bf16(fa0, fb0, acc00, 0, 0, 0);
    acc01 = __builtin_amdgcn_mfma_f32_16x16x32_bf16(fa0, fb1, acc01, 0, 0, 0);
    acc10 = __builtin_amdgcn_mfma_f32_16x16x32_bf16(fa1, fb0, acc10, 0, 0, 0);
    acc11 = __builtin_amdgcn_mfma_f32_16x16x32_bf16(fa1, fb1, acc11, 0, 0, 0);
    a0 = na0; a1 = na1; w0 = nw0; w1 = nw1;  // rotate prefetch regs
  }
  // C/D: col=lane&15, row=(lane>>4)*4+r  (bit-proven)
  const int colA = n0 + nq + fr;
  const int colB = colA + 16;
  const float biasA = (colA < 256) ? bh[colA] : 0.0f;
  const float biasB = (colB < 256) ? bh[colB] : 0.0f;
#pragma unroll
  for (int r = 0; r < 4; ++r) {
    int row0 = m0 + mq + kq * 4 + r;
    int row1 = row0 + 16;
    hc[(size_t)row0 * NTOT + colA] = __builtin_amdgcn_exp2f(KSCALE * (acc00[r] + biasA));
    hc[(size_t)row0 * NTOT + colB] = __builtin_amdgcn_exp2f(KSCALE * (acc01[r] + biasB));
    hc[(size_t)row1 * NTOT + colA] = __builtin_amdgcn_exp2f(KSCALE * (acc10[r] + biasA));
    hc[(size_t)row1 * NTOT + colB] = __builtin_amdgcn_exp2f(KSCALE * (acc11[r] + biasB));
  }
}

// ---- edge: out[b,i,j] = S + sum_d (-2w[d])*rcp(Eh[j,d]*Ec[i,d]+1) + mm_i + mm_j ----
// Unchanged from R12 (proven, ~1 us above the trans-pipe floor).
__global__ __launch_bounds__(256)
void edge_kernel(const float* __restrict__ hc, const float* __restrict__ wout,
                 const int* __restrict__ mask, float* __restrict__ out) {
  __shared__ float ldH[32 * LSTR];
  __shared__ float ldC[32 * LSTR];
  __shared__ float wS[256];
  __shared__ float red[256];
  const int t = threadIdx.x;
  const int b = blockIdx.z;
  const int i0 = blockIdx.y * 32;
  const int j0 = blockIdx.x * 32;
  const int sbase = b * SL;

  float w = wout[t];
  wS[t] = -2.0f * w;
  red[t] = w;

  for (int u = t; u < 32 * 64; u += 256) {
    int row = u >> 6;
    int c4 = (u & 63) << 2;
    f32x4 hv = *(const f32x4*)&hc[(size_t)(sbase + j0 + row) * NTOT + c4];        // Eh(j)
    f32x4 cv = *(const f32x4*)&hc[(size_t)(sbase + i0 + row) * NTOT + 256 + c4];  // Ec(i)
    *(f32x4*)&ldH[row * LSTR + c4] = hv;
    *(f32x4*)&ldC[row * LSTR + c4] = cv;
  }
  __syncthreads();
  for (int s = 128; s > 0; s >>= 1) {
    if (t < s) red[t] += red[t + s];
    __syncthreads();
  }
  const float S = red[0];

  const int tx = t & 15, ty = t >> 4;
  const float* hp0 = &ldH[tx * LSTR];
  const float* hp1 = &ldH[(tx + 16) * LSTR];
  const float* cp0 = &ldC[ty * LSTR];
  const float* cp1 = &ldC[(ty + 16) * LSTR];
  float a00 = 0.f, a01 = 0.f, a10 = 0.f, a11 = 0.f;

#pragma unroll 8
  for (int d = 0; d < 256; d += 4) {
    f32x4 h0 = *(const f32x4*)&hp0[d];
    f32x4 h1 = *(const f32x4*)&hp1[d];
    f32x4 c0 = *(const f32x4*)&cp0[d];
    f32x4 c1 = *(const f32x4*)&cp1[d];
    f32x4 w4 = *(const f32x4*)&wS[d];  // uniform addr -> LDS broadcast
#pragma unroll
    for (int e = 0; e < 4; ++e) {
      float he0 = h0[e], he1 = h1[e], ce0 = c0[e], ce1 = c1[e], we = w4[e];
      float r00 = __builtin_amdgcn_rcpf(ce0 * he0 + 1.0f);
      float r01 = __builtin_amdgcn_rcpf(ce0 * he1 + 1.0f);
      float r10 = __builtin_amdgcn_rcpf(ce1 * he0 + 1.0f);
      float r11 = __builtin_amdgcn_rcpf(ce1 * he1 + 1.0f);
      a00 = fmaf(we, r00, a00);
      a01 = fmaf(we, r01, a01);
      a10 = fmaf(we, r10, a10);
      a11 = fmaf(we, r11, a11);
    }
  }

  const int gi0 = sbase + i0 + ty, gi1 = gi0 + 16;   // out rows (i, child)
  const int gj0 = j0 + tx, gj1 = gj0 + 16;           // out cols (j, head)
  const float mi0 = (1.0f - (float)mask[gi0]) * -1.0e8f;
  const float mi1 = (1.0f - (float)mask[gi1]) * -1.0e8f;
  const float mj0 = (1.0f - (float)mask[sbase + gj0]) * -1.0e8f;
  const float mj1 = (1.0f - (float)mask[sbase + gj1]) * -1.0e8f;
  out[(size_t)gi0 * SL + gj0] = S + a00 + mi0 + mj0;
  out[(size_t)gi0 * SL + gj1] = S + a01 + mi0 + mj1;
  out[(size_t)gi1 * SL + gj0] = S + a10 + mi1 + mj0;
  out[(size_t)gi1 * SL + gj1] = S + a11 + mi1 + mj1;
}

extern "C" void kernel_launch(void* const* d_in, const int* in_sizes, int n_in,
                              void* d_out, int out_size, void* d_ws, size_t ws_size,
                              hipStream_t stream) {
  (void)in_sizes; (void)n_in; (void)out_size; (void)ws_size;
  const float* enc = (const float*)d_in[0];   // (8,256,1024) fp32
  const int* mask = (const int*)d_in[1];      // (8,256) int32
  const float* Wh = (const float*)d_in[2];    // (256,1024) fp32
  const float* bh = (const float*)d_in[3];    // (256,) fp32
  const float* Wc = (const float*)d_in[4];    // (256,1024) fp32
  const float* wout = (const float*)d_in[5];  // (256,) fp32
  float* out = (float*)d_out;

  float* hc = (float*)d_ws;  // 4 MiB (2048 x 512 f32, exp-domain)

  projc_kernel<<<dim3(32, 8), 256, 0, stream>>>(enc, Wh, Wc, bh, hc);
  edge_kernel<<<dim3(8, 8, 8), 256, 0, stream>>>(hc, wout, mask, out);
}